// Round 7
// baseline (1429.205 us; speedup 1.0000x reference)
//
#include <hip/hip_runtime.h>

// ============================================================================
// Fully-fused 3-layer Elman RNN, *** FP32 in/out ***, MFMA 16x16x32 bf16 via
// Ootomo 3-term double-bf16 products (wh*ah + wl*ah + wh*al, err ~2^-18).
//   B=8192, T=64, dims: 84 -> 128 -> 128 -> 84
// R10: de-phase via TWO independent blocks per CU.
//   R7-R9 data: round pinned at 13.4-14.9k cy; per-CU pipe sums MFMA 3.9k +
//   VALU 4.6k + LDS ~5k ~= round, each pipe only ~30% busy => the single
//   barrier phase-aligns all waves (read ramp -> MFMA burst -> VALU epilogue)
//   so pipes take turns. R9's dual-acc chains: MFMA busy time unchanged =>
//   dep-chain latency was NOT the limiter (C-forwarding); reverted.
//   Fix: 16 batch rows/block, grid 512 => 2 blocks/CU; blocks are not
//   barrier-synced so their phases interleave. MFMA 16x16x32 (M=16),
//   operand-swapped (weights=A): D feature=(lane>>4)*4+reg, batch=lane&15
//   (packed b64 epilogue preserved). LDS 64KB/block (2x64=128<=160).
//   3-role x 4-wave pipeline kept; wave 11 = stager. launch_bounds(768,6):
//   reg cap 341/wave, weights <=128 => no spill risk (R5 lesson).
// Pipeline depth 3, 66 rounds, ONE barrier/round (audit shape unchanged):
//   L0(t=rr) xb[P],h0[P]->h0[PN] | L1(t=rr-1) h0[P],h1[P]->h1[PN]
//   L2(t=rr-2) h1[P],h2[P]->h2[PN]+out | stagers x(rr+1)->xb[PN] (rr<=62)
//   Every producer->consumer gap exactly 1 round; parity dbuf sound.
// Numerics: same hi/lo paths; only fp32 summation grouping changes (K=32
// chunks vs K=16) -> few-ulp wiggle at most.
// ============================================================================

typedef __bf16 bf16x8 __attribute__((ext_vector_type(8)));
typedef float  f32x4  __attribute__((ext_vector_type(4)));
typedef unsigned short u16;
typedef unsigned int   u32;
typedef u16 u16x8 __attribute__((ext_vector_type(8)));
typedef u16 u16x4 __attribute__((ext_vector_type(4)));

#define MFMA16(a, b, c) __builtin_amdgcn_mfma_f32_16x16x32_bf16((a), (b), (c), 0, 0, 0)

__device__ __forceinline__ float bf2f(u16 v) {
    return __builtin_bit_cast(float, (u32)v << 16);
}
__device__ __forceinline__ u16 f2bf(float f) {   // RNE, finite inputs
    u32 u = __builtin_bit_cast(u32, f);
    u = u + 0x7fffu + ((u >> 16) & 1u);
    return (u16)(u >> 16);
}
__device__ __forceinline__ float tanh_fast(float x) {
    float xc = fminf(fmaxf(x, -12.f), 12.f);
    float e  = __expf(2.f * xc);
    return (e - 1.f) * __builtin_amdgcn_rcpf(e + 1.f);
}
__device__ __forceinline__ bf16x8 ld_lds8(const u16* p) {
    return __builtin_bit_cast(bf16x8, *(const u16x8*)p);
}
// plane index (u16 units): 16 rows x 128 cols, XOR-swizzled col.
// b128 reads at off mult of 8 (swizzle toggles bits 3..5 => 8-alignment
// kept); b64 writes at col%8 in {0,4} stay inside the 16B swizzle cell.
// Bank math: row*128 u16 = 64 words == 0 mod 32 banks => bank = f(swizzled
// col) only; both read and write patterns are 8-access/bank optimal.
__device__ __forceinline__ int aswz(int row, int off) {
    return row * 128 + (off ^ ((row & 7) << 3));
}
// pack 4 floats -> hi/lo bf16 quads, one ds_write_b64 per plane
__device__ __forceinline__ void store4_hl(u16* ph, u16* pl, f32x4 v) {
    u16x4 hi, lo;
#pragma unroll
    for (int j = 0; j < 4; j++) {
        u16 h = f2bf(v[j]);
        hi[j] = h;
        lo[j] = f2bf(v[j] - bf2f(h));
    }
    *(u16x4*)ph = hi;
    *(u16x4*)pl = lo;
}
__device__ __forceinline__ f32x4 tanh4(f32x4 a) {
    f32x4 r;
#pragma unroll
    for (int j = 0; j < 4; j++) r[j] = tanh_fast(a[j]);
    return r;
}

struct fragp { bf16x8 h, l; };

// Weight A-frag pair, W fp32 row-major [Hr][Kr]; lane holds W[n][kbase..+8)
// split hi/lo. Zero-pads OOB rows/cols. 16x16x32 operand map (verified
// R1-R6): lane l holds op[dim16 = l&15][k = (l>>4)*8 + j] for BOTH A and B.
__device__ __forceinline__ fragp load_wfrag_hl(const float* W, int Hr, int Kr,
                                               int n, int kbase) {
    u16x8 uh = {0,0,0,0,0,0,0,0}, ul = {0,0,0,0,0,0,0,0};
    if (n < Hr) {
#pragma unroll
        for (int j = 0; j < 8; j++) {
            int k = kbase + j;
            if (k < Kr) {
                float w = W[n * Kr + k];
                u16 hi = f2bf(w);
                uh[j] = hi;
                ul[j] = f2bf(w - bf2f(hi));
            }
        }
    }
    fragp r;
    r.h = __builtin_bit_cast(bf16x8, uh);
    r.l = __builtin_bit_cast(bf16x8, ul);
    return r;
}

// 3-term double-bf16 accumulate, swapped operands: D += (Wh+Wl)(Ah+Al)
// D: feature = (lane>>4)*4 + reg (A's 16-dim), batch = lane&15 (B's 16-dim)
__device__ __forceinline__ f32x4 mm3s(const fragp& w, bf16x8 ah, bf16x8 al, f32x4 c) {
    c = MFMA16(w.h, ah, c);
    c = MFMA16(w.l, ah, c);
    c = MFMA16(w.h, al, c);
    return c;
}

// ---- x staging: 336 float4 quads (16 rows x 21). 5 stager waves (0-3, 11)
// = 320 lanes; slot0 = sid, slot1 = sid+320 (valid iff sid<16). Issue-early
// (round top) / write-late (after compute), hoisted addresses.
#define STG_SETUP()                                                      \
    int g0o, l0o, g1o, l1o;                                              \
    const bool has1 = (sid < 16);                                        \
    {                                                                    \
        int r0 = sid / 21, c0 = (sid - r0 * 21) * 4;                     \
        g0o = r0 * 5376 + c0; l0o = aswz(r0, c0);                        \
        int s1 = sid + 320, r1 = s1 / 21, c1 = (s1 - r1 * 21) * 4;       \
        g1o = r1 * 5376 + c1; l1o = aswz(r1, c1);                        \
    }                                                                    \
    f32x4 xq0, xq1;
#define STG_ISSUE(trr)                                                   \
    {                                                                    \
        const int tofs = (trr) * 84;                                     \
        xq0 = *(const f32x4*)&xg[g0o + tofs];                            \
        if (has1) xq1 = *(const f32x4*)&xg[g1o + tofs];                  \
    }
#define STG_WRITE(PNv)                                                   \
    {                                                                    \
        store4_hl(&xbh[(PNv)][l0o], &xbl[(PNv)][l0o], xq0);              \
        if (has1) store4_hl(&xbh[(PNv)][l1o], &xbl[(PNv)][l1o], xq1);    \
    }

__global__ __launch_bounds__(768, 6)  // 12 waves/block, 2 blocks/CU, 6 waves/SIMD
void rnn_fused(const float* __restrict__ x,
               const float* __restrict__ wih0, const float* __restrict__ whh0,
               const float* __restrict__ bih0, const float* __restrict__ bhh0,
               const float* __restrict__ wih1, const float* __restrict__ whh1,
               const float* __restrict__ bih1, const float* __restrict__ bhh1,
               const float* __restrict__ wih2, const float* __restrict__ whh2,
               const float* __restrict__ bih2, const float* __restrict__ bhh2,
               float* __restrict__ out)
{
    // hi/lo planes, [parity][16 rows x 128 cols swizzled] u16. 64 KiB total.
    __shared__ __align__(16) u16 h0h[2][2048], h0l[2][2048];
    __shared__ __align__(16) u16 h1h[2][2048], h1l[2][2048];
    __shared__ __align__(16) u16 h2h[2][2048], h2l[2][2048];
    __shared__ __align__(16) u16 xbh[2][2048], xbl[2][2048];

    const int tid  = threadIdx.x;
    const int wv   = tid >> 6;        // wave 0..11
    const int lane = tid & 63;
    const int ln   = lane & 15;       // batch row (D col) / op 16-dim
    const int q    = lane >> 4;       // k-quad; D rows q*4..q*4+3
    const int b0   = blockIdx.x * 16;
    const float* xg = x + (long)b0 * 5376;

    // ---- prologue: zero first-READ parities (L0@rr=0 reads h0[0];
    // L1@rr=1 reads h1[1]; L2@rr=2 reads h2[0]); xb fully zeroed (pad cols).
    for (int i = tid; i < 2048; i += 768) {
        h0h[0][i] = 0; h0l[0][i] = 0;
        h1h[1][i] = 0; h1l[1][i] = 0;
        h2h[0][i] = 0; h2l[0][i] = 0;
    }
    { u16* z = &xbh[0][0]; for (int i = tid; i < 4096; i += 768) z[i] = 0; }
    { u16* z = &xbl[0][0]; for (int i = tid; i < 4096; i += 768) z[i] = 0; }
    __syncthreads();   // xb zero visible before x(0) staging overlays it
    // stage x(0) -> xb[0]
    for (int s = tid; s < 336; s += 768) {
        int row = s / 21, col = (s - row * 21) * 4;
        f32x4 v = *(const f32x4*)&xg[(long)row * 5376 + col];
        int idx = aswz(row, col);
        store4_hl(&xbh[0][idx], &xbl[0][idx], v);
    }
    __syncthreads();   // prologue barrier (uniform)

    if (wv < 4) {
        // ================= L0-role: t = rr, rr in [0,63] =================
        const int nb = wv * 32;
        fragp fih0[2][3], fhh0[2][4];
#pragma unroll
        for (int f = 0; f < 2; f++) {
#pragma unroll
            for (int c = 0; c < 3; c++)
                fih0[f][c] = load_wfrag_hl(wih0, 128, 84, nb + f * 16 + ln, c * 32 + q * 8);
#pragma unroll
            for (int c = 0; c < 4; c++)
                fhh0[f][c] = load_wfrag_hl(whh0, 128, 128, nb + f * 16 + ln, c * 32 + q * 8);
        }
        f32x4 bias0v[2];
#pragma unroll
        for (int f = 0; f < 2; f++) {
            const int fb = nb + f * 16 + q * 4;
            bias0v[f] = *(const f32x4*)&bih0[fb] + *(const f32x4*)&bhh0[fb];
        }
        const int sid = wv * 64 + lane;     // stager slots 0..255
        STG_SETUP();

        for (int rr = 0; rr < 66; ++rr) {
            const int P = rr & 1, PN = P ^ 1;
            if (rr <= 62) STG_ISSUE(rr + 1);
            if (rr <= 63) {
                f32x4 a0 = bias0v[0], a1 = bias0v[1];
                __builtin_amdgcn_s_setprio(1);
#pragma unroll
                for (int c = 0; c < 3; c++) {      // proj from xb
                    const int idx = aswz(ln, c * 32 + q * 8);
                    bf16x8 bh = ld_lds8(&xbh[P][idx]), bl = ld_lds8(&xbl[P][idx]);
                    a0 = mm3s(fih0[0][c], bh, bl, a0);
                    a1 = mm3s(fih0[1][c], bh, bl, a1);
                }
#pragma unroll
                for (int c = 0; c < 4; c++) {      // recurrence from h0
                    const int idx = aswz(ln, c * 32 + q * 8);
                    bf16x8 bh = ld_lds8(&h0h[P][idx]), bl = ld_lds8(&h0l[P][idx]);
                    a0 = mm3s(fhh0[0][c], bh, bl, a0);
                    a1 = mm3s(fhh0[1][c], bh, bl, a1);
                }
                __builtin_amdgcn_s_setprio(0);
                {
                    f32x4 v0 = tanh4(a0), v1 = tanh4(a1);
                    const int i0 = aswz(ln, nb + q * 4);
                    const int i1 = aswz(ln, nb + 16 + q * 4);
                    store4_hl(&h0h[PN][i0], &h0l[PN][i0], v0);
                    store4_hl(&h0h[PN][i1], &h0l[PN][i1], v1);
                }
            }
            if (rr <= 62) STG_WRITE(PN);
            __syncthreads();
        }
    } else if (wv < 8) {
        // ================= L1-role: t = rr-1, rr in [1,64] =================
        const int nb = (wv - 4) * 32;
        fragp fih1[2][4], fhh1[2][4];
#pragma unroll
        for (int f = 0; f < 2; f++) {
#pragma unroll
            for (int c = 0; c < 4; c++) {
                fih1[f][c] = load_wfrag_hl(wih1, 128, 128, nb + f * 16 + ln, c * 32 + q * 8);
                fhh1[f][c] = load_wfrag_hl(whh1, 128, 128, nb + f * 16 + ln, c * 32 + q * 8);
            }
        }
        f32x4 bias1v[2];
#pragma unroll
        for (int f = 0; f < 2; f++) {
            const int fb = nb + f * 16 + q * 4;
            bias1v[f] = *(const f32x4*)&bih1[fb] + *(const f32x4*)&bhh1[fb];
        }
        for (int rr = 0; rr < 66; ++rr) {
            const int P = rr & 1, PN = P ^ 1;
            if (rr >= 1 && rr <= 64) {
                f32x4 a0 = bias1v[0], a1 = bias1v[1];
                __builtin_amdgcn_s_setprio(1);
#pragma unroll
                for (int c = 0; c < 4; c++) {      // proj from h0
                    const int idx = aswz(ln, c * 32 + q * 8);
                    bf16x8 bh = ld_lds8(&h0h[P][idx]), bl = ld_lds8(&h0l[P][idx]);
                    a0 = mm3s(fih1[0][c], bh, bl, a0);
                    a1 = mm3s(fih1[1][c], bh, bl, a1);
                }
#pragma unroll
                for (int c = 0; c < 4; c++) {      // recurrence from h1
                    const int idx = aswz(ln, c * 32 + q * 8);
                    bf16x8 bh = ld_lds8(&h1h[P][idx]), bl = ld_lds8(&h1l[P][idx]);
                    a0 = mm3s(fhh1[0][c], bh, bl, a0);
                    a1 = mm3s(fhh1[1][c], bh, bl, a1);
                }
                __builtin_amdgcn_s_setprio(0);
                {
                    f32x4 v0 = tanh4(a0), v1 = tanh4(a1);
                    const int i0 = aswz(ln, nb + q * 4);
                    const int i1 = aswz(ln, nb + 16 + q * 4);
                    store4_hl(&h1h[PN][i0], &h1l[PN][i0], v0);
                    store4_hl(&h1h[PN][i1], &h1l[PN][i1], v1);
                }
            }
            __syncthreads();
        }
    } else if (wv < 11) {
        // ================= L2-role: t = rr-2, rr in [2,65] =================
        const int nb = (wv - 8) * 32;              // cols 0..95 (84 live)
        fragp fih2[2][4], fhh2[2][3];
#pragma unroll
        for (int f = 0; f < 2; f++) {
#pragma unroll
            for (int c = 0; c < 4; c++)
                fih2[f][c] = load_wfrag_hl(wih2, 84, 128, nb + f * 16 + ln, c * 32 + q * 8);
#pragma unroll
            for (int c = 0; c < 3; c++)
                fhh2[f][c] = load_wfrag_hl(whh2, 84, 84, nb + f * 16 + ln, c * 32 + q * 8);
        }
        f32x4 bias2v[2];
#pragma unroll
        for (int f = 0; f < 2; f++) {
            const int fb = nb + f * 16 + q * 4;
            if (fb < 84) bias2v[f] = *(const f32x4*)&bih2[fb] + *(const f32x4*)&bhh2[fb];
            else { bias2v[f][0]=0.f; bias2v[f][1]=0.f; bias2v[f][2]=0.f; bias2v[f][3]=0.f; }
        }
        for (int rr = 0; rr < 66; ++rr) {
            const int P = rr & 1, PN = P ^ 1;
            if (rr >= 2) {
                const int t2 = rr - 2;
                f32x4 a0 = bias2v[0], a1 = bias2v[1];
                __builtin_amdgcn_s_setprio(1);
#pragma unroll
                for (int c = 0; c < 4; c++) {      // proj from h1
                    const int idx = aswz(ln, c * 32 + q * 8);
                    bf16x8 bh = ld_lds8(&h1h[P][idx]), bl = ld_lds8(&h1l[P][idx]);
                    a0 = mm3s(fih2[0][c], bh, bl, a0);
                    a1 = mm3s(fih2[1][c], bh, bl, a1);
                }
#pragma unroll
                for (int c = 0; c < 3; c++) {      // recurrence from h2 (K=96 pad)
                    const int idx = aswz(ln, c * 32 + q * 8);
                    bf16x8 bh = ld_lds8(&h2h[P][idx]), bl = ld_lds8(&h2l[P][idx]);
                    a0 = mm3s(fhh2[0][c], bh, bl, a0);
                    a1 = mm3s(fhh2[1][c], bh, bl, a1);
                }
                __builtin_amdgcn_s_setprio(0);
                {
                    f32x4 v0 = tanh4(a0), v1 = tanh4(a1);
                    const int fb0 = nb + q * 4, fb1 = nb + 16 + q * 4;
                    const int i0 = aswz(ln, fb0), i1 = aswz(ln, fb1);
                    store4_hl(&h2h[PN][i0], &h2l[PN][i0], v0);   // zeros at fb>=84
                    store4_hl(&h2h[PN][i1], &h2l[PN][i1], v1);
                    float* ob = out + (long)(b0 + ln) * 5376 + t2 * 84;
                    if (fb0 < 84) *(f32x4*)(ob + fb0) = v0;      // 84%4==0
                    if (fb1 < 84) *(f32x4*)(ob + fb1) = v1;
                }
            }
            __syncthreads();
        }
    } else {
        // ================= wave 11: stager-only =================
        const int sid = 256 + lane;                // stager slots 256..319
        STG_SETUP();
        for (int rr = 0; rr < 66; ++rr) {
            const int PN = (rr & 1) ^ 1;
            if (rr <= 62) STG_ISSUE(rr + 1);
            if (rr <= 62) STG_WRITE(PN);
            __syncthreads();
        }
    }
}

extern "C" void kernel_launch(void* const* d_in, const int* in_sizes, int n_in,
                              void* d_out, int out_size, void* d_ws, size_t ws_size,
                              hipStream_t stream) {
    (void)in_sizes; (void)n_in; (void)out_size; (void)d_ws; (void)ws_size;
    const float* x    = (const float*)d_in[0];
    const float* wih0 = (const float*)d_in[1];
    const float* whh0 = (const float*)d_in[2];
    const float* bih0 = (const float*)d_in[3];
    const float* bhh0 = (const float*)d_in[4];
    const float* wih1 = (const float*)d_in[5];
    const float* whh1 = (const float*)d_in[6];
    const float* bih1 = (const float*)d_in[7];
    const float* bhh1 = (const float*)d_in[8];
    const float* wih2 = (const float*)d_in[9];
    const float* whh2 = (const float*)d_in[10];
    const float* bih2 = (const float*)d_in[11];
    const float* bhh2 = (const float*)d_in[12];
    float* out = (float*)d_out;

    rnn_fused<<<dim3(8192 / 16), dim3(768), 0, stream>>>(
        x, wih0, whh0, bih0, bhh0, wih1, whh1, bih1, bhh1,
        wih2, whh2, bih2, bhh2, out);
}

// Round 8
// 496.580 us; speedup vs baseline: 2.8781x; 2.8781x over previous
//
#include <hip/hip_runtime.h>

// ============================================================================
// Fully-fused 3-layer Elman RNN, *** FP32 in/out ***, MFMA 32x32x16 bf16 via
// Ootomo 3-term double-bf16 products (wh*ah + wl*ah + wh*al, err ~2^-18).
//   B=8192, T=64, dims: 84 -> 128 -> 128 -> 84
// R11 = R8 structure (best, 369us) + instruction-level trims.
//   R10 post-mortem: launch_bounds(768,6) capped waves at ~85 regs < 112-reg
//   weight sets -> compiler REMATERIALIZED weight loads in-loop (VGPR=40,
//   FETCH 104MB->4.1GB, HBM 47%). 2 blocks/CU is structurally incompatible
//   with register-resident weights. R9 decomposed: dual-acc chain was the
//   regression (MFMA-busy unchanged => dep chain never critical; C-forwarded);
//   xb-swizzle + quad-staging kept.
//   R8 counters: VALU 4.8k cy/round ~= entirely epilogue conversion math
//   (tanh ~9 + manual f2bf bit-twiddle ~8 per value); barrier = full
//   vmcnt(0)+lgkmcnt(0) drain -> L2 waves wait on out-store retirement.
// Changes (structure frozen):
//   1) native (__bf16) casts for f32->bf16 (compiler fuses v_cvt_pk_bf16_f32;
//      m240: casts not inline-asm). RNE == old manual RNE -> bit-identical.
//   2) tanh = 1 - 2*rcp(e+1) via fma (one fewer dependent VALU op).
//   3) round barrier = raw s_barrier + lgkmcnt(0)-only (sched_barrier-fenced,
//      T3/T4 pattern): out-stores/staging loads retire off the critical path;
//      LDS producer->consumer visibility fully preserved by lgkmcnt(0).
//   4) single acc chain (R9 revert); xb swizzled planes + float4-quad staging.
// Pipeline: 3 roles x 4 waves (L0 wv0-3, L1 wv4-7, L2 wv8-10, stager wv11),
// 66 rounds, ONE barrier/round; round rr (P=rr&1, PN=P^1):
//   L0(t=rr) xb[P],h0[P]->h0[PN] | L1(t=rr-1) h0[P],h1[P]->h1[PN]
//   L2(t=rr-2) h1[P],h2[P]->h2[PN]+out | stagers x(rr+1)->xb[PN] (rr<=62)
// Every producer->consumer gap exactly 1 round (R6-R9 audit shape).
// ============================================================================

typedef __bf16 bf16x8 __attribute__((ext_vector_type(8)));
typedef float  f32x4  __attribute__((ext_vector_type(4)));
typedef float  f32x16 __attribute__((ext_vector_type(16)));
typedef unsigned short u16;
typedef unsigned int   u32;
typedef u16 u16x8 __attribute__((ext_vector_type(8)));
typedef u16 u16x4 __attribute__((ext_vector_type(4)));

#define MFMA32(a, b, c) __builtin_amdgcn_mfma_f32_32x32x16_bf16((a), (b), (c), 0, 0, 0)

__device__ __forceinline__ float bf2f(u16 v) {
    return __builtin_bit_cast(float, (u32)v << 16);
}
__device__ __forceinline__ u16 f2bf(float f) {   // RNE bit-twiddle (prologue only)
    u32 u = __builtin_bit_cast(u32, f);
    u = u + 0x7fffu + ((u >> 16) & 1u);
    return (u16)(u >> 16);
}
__device__ __forceinline__ float tanh_fast(float x) {
    float xc = fminf(fmaxf(x, -12.f), 12.f);
    float e  = __expf(2.f * xc);
    float r  = __builtin_amdgcn_rcpf(e + 1.f);
    return __builtin_fmaf(-2.f, r, 1.f);          // 1 - 2/(e+1) == (e-1)/(e+1)
}
__device__ __forceinline__ bf16x8 ld_lds8(const u16* p) {
    return __builtin_bit_cast(bf16x8, *(const u16x8*)p);
}
// plane index (u16 units): row stride 128, XOR-swizzled col. b128 reads at
// off mult of 8 (swizzle toggles bits 3..5); b64 writes at col mult of 4
// stay inside the 16B cell. 64-word rows == 0 mod 32 banks => bank = f(col
// swizzled) only; read and write patterns are 8-/4-access-per-bank optimal.
__device__ __forceinline__ int aswz(int row, int off) {
    return row * 128 + (off ^ ((row & 7) << 3));
}
// pack 4 floats -> hi/lo bf16 quads via NATIVE casts (cvt_pk fusable),
// one ds_write_b64 per plane.
__device__ __forceinline__ void store4_hl(u16* ph, u16* pl, f32x4 v) {
    u16x4 hi, lo;
#pragma unroll
    for (int j = 0; j < 4; j++) {
        __bf16 h = (__bf16)v[j];
        hi[j] = __builtin_bit_cast(u16, h);
        __bf16 l = (__bf16)(v[j] - bf2f(hi[j]));
        lo[j] = __builtin_bit_cast(u16, l);
    }
    *(u16x4*)ph = hi;
    *(u16x4*)pl = lo;
}

struct fragp { bf16x8 h, l; };

// Weight A-frag pair, W fp32 row-major [Hr][Kr]; lane holds W[n][kbase..+8)
// split hi/lo. Zero-pads OOB rows/cols. (32x32x16 map: row=lane&31,
// k=(lane>>5)*8+j — caller passes n=nb+(lane&31), kbase=c*16+(lane>>5)*8.)
__device__ __forceinline__ fragp load_wfrag_hl(const float* W, int Hr, int Kr,
                                               int n, int kbase) {
    u16x8 uh = {0,0,0,0,0,0,0,0}, ul = {0,0,0,0,0,0,0,0};
    if (n < Hr) {
#pragma unroll
        for (int j = 0; j < 8; j++) {
            int k = kbase + j;
            if (k < Kr) {
                float w = W[n * Kr + k];
                u16 hi = f2bf(w);
                uh[j] = hi;
                ul[j] = f2bf(w - bf2f(hi));
            }
        }
    }
    fragp r;
    r.h = __builtin_bit_cast(bf16x8, uh);
    r.l = __builtin_bit_cast(bf16x8, ul);
    return r;
}

// 3-term double-bf16 accumulate, swapped operands: D += (Wh+Wl)(Ah+Al)
__device__ __forceinline__ f32x16 mm3t(const fragp& w, bf16x8 ah, bf16x8 al, f32x16 c) {
    c = MFMA32(w.h, ah, c);
    c = MFMA32(w.l, ah, c);
    c = MFMA32(w.h, al, c);
    return c;
}

// Round barrier: lgkmcnt(0)-only drain + raw s_barrier (T3/T4 pattern).
// LDS writes are visible (lgkmcnt(0)); global out-stores / staging loads
// intentionally NOT drained (nothing reads them across the barrier).
#define ROUND_BARRIER() do {                                             \
    asm volatile("s_waitcnt lgkmcnt(0)" ::: "memory");                   \
    __builtin_amdgcn_sched_barrier(0);                                   \
    __builtin_amdgcn_s_barrier();                                        \
    __builtin_amdgcn_sched_barrier(0);                                   \
} while (0)

// ---- quad staging: 672 float4 slots (32 rows x 21 quads). Stagers are the
// 512 threads of waves 0-3 / 8-11; slot0 = tid_s, slot1 = tid_s+512 (<672
// iff tid_s<160). Addresses hoisted; issue-early / write-late split.
#define STG_ISSUE(trr)                                                   \
    {                                                                    \
        const int tofs = (trr) * 84;                                     \
        xq0 = *(const f32x4*)&xg[goffq0 + tofs];                         \
        if (tid_s < 160) xq1 = *(const f32x4*)&xg[goffq1 + tofs];        \
    }
#define STG_WRITE(PNv)                                                   \
    {                                                                    \
        u16* bh = &xbh[(PNv)][0];                                        \
        u16* bl = &xbl[(PNv)][0];                                        \
        store4_hl(&bh[lofsq0], &bl[lofsq0], xq0);                        \
        if (tid_s < 160) store4_hl(&bh[lofsq1], &bl[lofsq1], xq1);       \
    }
#define STG_SETUP()                                                      \
    int goffq0, lofsq0, goffq1, lofsq1;                                  \
    {                                                                    \
        int r0 = tid_s / 21, c0 = (tid_s - r0 * 21) * 4;                 \
        goffq0 = r0 * 5376 + c0;                                         \
        lofsq0 = r0 * 128 + (c0 ^ ((r0 & 7) << 3));                      \
        int s1 = tid_s + 512, r1 = s1 / 21, c1 = (s1 - r1 * 21) * 4;     \
        goffq1 = r1 * 5376 + c1;                                         \
        lofsq1 = r1 * 128 + (c1 ^ ((r1 & 7) << 3));                      \
    }                                                                    \
    f32x4 xq0, xq1;

__global__ __launch_bounds__(768, 3)  // 12 waves, 3/SIMD (R8's proven config)
void rnn_fused(const float* __restrict__ x,
               const float* __restrict__ wih0, const float* __restrict__ whh0,
               const float* __restrict__ bih0, const float* __restrict__ bhh0,
               const float* __restrict__ wih1, const float* __restrict__ whh1,
               const float* __restrict__ bih1, const float* __restrict__ bhh1,
               const float* __restrict__ wih2, const float* __restrict__ whh2,
               const float* __restrict__ bih2, const float* __restrict__ bhh2,
               float* __restrict__ out)
{
    // activation + x hi/lo planes, [parity][32 rows x 128 cols swizzled] u16
    __shared__ __align__(16) u16 h0h[2][4096], h0l[2][4096];
    __shared__ __align__(16) u16 h1h[2][4096], h1l[2][4096];
    __shared__ __align__(16) u16 h2h[2][4096], h2l[2][4096];
    __shared__ __align__(16) u16 xbh[2][4096], xbl[2][4096];
    __shared__ float biasF[3][128];               // combined biases per layer

    const int tid  = threadIdx.x;
    const int wv   = tid >> 6;        // wave 0..11
    const int lane = tid & 63;
    const int mrow = lane & 31;       // batch row (D col after operand swap)
    const int q2   = lane >> 5;       // k-half
    const int kq   = q2 * 8;
    const int q4   = q2 * 4;
    const int b0   = blockIdx.x * 32;
    const float* xg = x + (long)b0 * 5376;

    // ---- prologue: zero first-READ parities (L0@rr=0 reads h0[0];
    // L1@rr=1 reads h1[1]; L2@rr=2 reads h2[0]); xb fully zeroed (pad cols).
    { u16* z = &h0h[0][0]; for (int i = tid; i < 4096; i += 768) z[i] = 0; }
    { u16* z = &h0l[0][0]; for (int i = tid; i < 4096; i += 768) z[i] = 0; }
    { u16* z = &h1h[1][0]; for (int i = tid; i < 4096; i += 768) z[i] = 0; }
    { u16* z = &h1l[1][0]; for (int i = tid; i < 4096; i += 768) z[i] = 0; }
    { u16* z = &h2h[0][0]; for (int i = tid; i < 4096; i += 768) z[i] = 0; }
    { u16* z = &h2l[0][0]; for (int i = tid; i < 4096; i += 768) z[i] = 0; }
    { u16* z = &xbh[0][0]; for (int i = tid; i < 8192; i += 768) z[i] = 0; }
    { u16* z = &xbl[0][0]; for (int i = tid; i < 8192; i += 768) z[i] = 0; }
    __syncthreads();   // xb zero visible before x(0) staging overlays it
    // stage x(0) -> xb[0] via quads
    for (int s = tid; s < 672; s += 768) {
        int row = s / 21, cq = (s - row * 21) * 4;
        f32x4 v = *(const f32x4*)&xg[(long)row * 5376 + cq];
        int idx = row * 128 + (cq ^ ((row & 7) << 3));
        store4_hl(&xbh[0][idx], &xbl[0][idx], v);
    }
    // combined biases (pad cols -> 0)
    for (int i = tid; i < 384; i += 768) {
        int l = i >> 7, n = i & 127;
        float v = 0.f;
        if (l == 0)      v = bih0[n] + bhh0[n];
        else if (l == 1) v = bih1[n] + bhh1[n];
        else if (n < 84) v = bih2[n] + bhh2[n];
        biasF[l][n] = v;
    }
    __syncthreads();   // prologue barrier (uniform, full drain: fine once)

    if (wv < 4) {
        // ================= L0-role: t = rr, rr in [0,63] =================
        const int nb = wv * 32;
        fragp fih0[6], fhh0[8];
#pragma unroll
        for (int c = 0; c < 6; c++)
            fih0[c] = load_wfrag_hl(wih0, 128, 84, nb + mrow, c * 16 + kq);
#pragma unroll
        for (int c = 0; c < 8; c++)
            fhh0[c] = load_wfrag_hl(whh0, 128, 128, nb + mrow, c * 16 + kq);
        const int tid_s = wv * 64 + lane;      // stager slot base (0..255)
        STG_SETUP();

        for (int rr = 0; rr < 66; ++rr) {
            const int P = rr & 1, PN = P ^ 1;
            if (rr <= 62) STG_ISSUE(rr + 1);
            if (rr <= 63) {
                f32x16 acc;
#pragma unroll
                for (int g = 0; g < 4; g++) {
                    f32x4 v = *(const f32x4*)&biasF[0][nb + g * 8 + q4];
                    acc[4*g+0] = v[0]; acc[4*g+1] = v[1];
                    acc[4*g+2] = v[2]; acc[4*g+3] = v[3];
                }
                __builtin_amdgcn_s_setprio(1);
#pragma unroll
                for (int c = 0; c < 6; c++) {      // proj from xb (swizzled)
                    const int idx = aswz(mrow, c * 16 + kq);
                    acc = mm3t(fih0[c], ld_lds8(&xbh[P][idx]), ld_lds8(&xbl[P][idx]), acc);
                }
#pragma unroll
                for (int c = 0; c < 8; c++) {      // recurrence from h0
                    const int idx = aswz(mrow, c * 16 + kq);
                    acc = mm3t(fhh0[c], ld_lds8(&h0h[P][idx]), ld_lds8(&h0l[P][idx]), acc);
                }
                __builtin_amdgcn_s_setprio(0);
#pragma unroll
                for (int g = 0; g < 4; g++) {
                    const int col = nb + g * 8 + q4;
                    f32x4 v;
                    v[0] = tanh_fast(acc[4*g+0]); v[1] = tanh_fast(acc[4*g+1]);
                    v[2] = tanh_fast(acc[4*g+2]); v[3] = tanh_fast(acc[4*g+3]);
                    const int idx = mrow * 128 + (col ^ ((mrow & 7) << 3));
                    store4_hl(&h0h[PN][idx], &h0l[PN][idx], v);
                }
            }
            if (rr <= 62) STG_WRITE(PN);
            ROUND_BARRIER();
        }
    } else if (wv < 8) {
        // ================= L1-role: t = rr-1, rr in [1,64] =================
        const int nb = (wv - 4) * 32;
        fragp fih1[8], fhh1[8];
#pragma unroll
        for (int c = 0; c < 8; c++) {
            fih1[c] = load_wfrag_hl(wih1, 128, 128, nb + mrow, c * 16 + kq);
            fhh1[c] = load_wfrag_hl(whh1, 128, 128, nb + mrow, c * 16 + kq);
        }
        for (int rr = 0; rr < 66; ++rr) {
            const int P = rr & 1, PN = P ^ 1;
            if (rr >= 1 && rr <= 64) {
                f32x16 acc;
#pragma unroll
                for (int g = 0; g < 4; g++) {
                    f32x4 v = *(const f32x4*)&biasF[1][nb + g * 8 + q4];
                    acc[4*g+0] = v[0]; acc[4*g+1] = v[1];
                    acc[4*g+2] = v[2]; acc[4*g+3] = v[3];
                }
                __builtin_amdgcn_s_setprio(1);
#pragma unroll
                for (int c = 0; c < 8; c++) {      // proj from h0
                    const int idx = aswz(mrow, c * 16 + kq);
                    acc = mm3t(fih1[c], ld_lds8(&h0h[P][idx]), ld_lds8(&h0l[P][idx]), acc);
                }
#pragma unroll
                for (int c = 0; c < 8; c++) {      // recurrence from h1
                    const int idx = aswz(mrow, c * 16 + kq);
                    acc = mm3t(fhh1[c], ld_lds8(&h1h[P][idx]), ld_lds8(&h1l[P][idx]), acc);
                }
                __builtin_amdgcn_s_setprio(0);
#pragma unroll
                for (int g = 0; g < 4; g++) {
                    const int col = nb + g * 8 + q4;
                    f32x4 v;
                    v[0] = tanh_fast(acc[4*g+0]); v[1] = tanh_fast(acc[4*g+1]);
                    v[2] = tanh_fast(acc[4*g+2]); v[3] = tanh_fast(acc[4*g+3]);
                    const int idx = mrow * 128 + (col ^ ((mrow & 7) << 3));
                    store4_hl(&h1h[PN][idx], &h1l[PN][idx], v);
                }
            }
            ROUND_BARRIER();
        }
    } else if (wv < 11) {
        // ================= L2-role: t = rr-2, rr in [2,65] =================
        const int nb = (wv - 8) * 32;              // cols 0..95 (84 live)
        fragp fih2[8], fhh2[6];
#pragma unroll
        for (int c = 0; c < 8; c++)
            fih2[c] = load_wfrag_hl(wih2, 84, 128, nb + mrow, c * 16 + kq);
#pragma unroll
        for (int c = 0; c < 6; c++)
            fhh2[c] = load_wfrag_hl(whh2, 84, 84, nb + mrow, c * 16 + kq);
        const int tid_s = (wv - 4) * 64 + lane;    // stager slots 256..447
        STG_SETUP();

        for (int rr = 0; rr < 66; ++rr) {
            const int P = rr & 1, PN = P ^ 1;
            if (rr <= 62) STG_ISSUE(rr + 1);
            if (rr >= 2) {
                const int t2 = rr - 2;
                f32x16 acc;
#pragma unroll
                for (int g = 0; g < 4; g++) {
                    f32x4 v = *(const f32x4*)&biasF[2][nb + g * 8 + q4];
                    acc[4*g+0] = v[0]; acc[4*g+1] = v[1];
                    acc[4*g+2] = v[2]; acc[4*g+3] = v[3];
                }
                __builtin_amdgcn_s_setprio(1);
#pragma unroll
                for (int c = 0; c < 8; c++) {      // proj from h1
                    const int idx = aswz(mrow, c * 16 + kq);
                    acc = mm3t(fih2[c], ld_lds8(&h1h[P][idx]), ld_lds8(&h1l[P][idx]), acc);
                }
#pragma unroll
                for (int c = 0; c < 6; c++) {      // recurrence from h2
                    const int idx = aswz(mrow, c * 16 + kq);
                    acc = mm3t(fhh2[c], ld_lds8(&h2h[P][idx]), ld_lds8(&h2l[P][idx]), acc);
                }
                __builtin_amdgcn_s_setprio(0);
#pragma unroll
                for (int g = 0; g < 4; g++) {
                    const int col = nb + g * 8 + q4;
                    f32x4 v;
                    v[0] = tanh_fast(acc[4*g+0]); v[1] = tanh_fast(acc[4*g+1]);
                    v[2] = tanh_fast(acc[4*g+2]); v[3] = tanh_fast(acc[4*g+3]);
                    const int idx = mrow * 128 + (col ^ ((mrow & 7) << 3));
                    store4_hl(&h2h[PN][idx], &h2l[PN][idx], v);
                    if (col < 84)   // 84%4==0 -> all-or-nothing per quad
                        *(f32x4*)(out + (long)(b0 + mrow) * 5376 + t2 * 84 + col) = v;
                }
            }
            if (rr <= 62) STG_WRITE(PN);
            ROUND_BARRIER();
        }
    } else {
        // ================= wave 11: stager-only =================
        const int tid_s = 7 * 64 + lane;           // stager slots 448..511
        STG_SETUP();
        for (int rr = 0; rr < 66; ++rr) {
            const int PN = (rr & 1) ^ 1;
            if (rr <= 62) STG_ISSUE(rr + 1);
            if (rr <= 62) STG_WRITE(PN);
            ROUND_BARRIER();
        }
    }
}

extern "C" void kernel_launch(void* const* d_in, const int* in_sizes, int n_in,
                              void* d_out, int out_size, void* d_ws, size_t ws_size,
                              hipStream_t stream) {
    (void)in_sizes; (void)n_in; (void)out_size; (void)d_ws; (void)ws_size;
    const float* x    = (const float*)d_in[0];
    const float* wih0 = (const float*)d_in[1];
    const float* whh0 = (const float*)d_in[2];
    const float* bih0 = (const float*)d_in[3];
    const float* bhh0 = (const float*)d_in[4];
    const float* wih1 = (const float*)d_in[5];
    const float* whh1 = (const float*)d_in[6];
    const float* bih1 = (const float*)d_in[7];
    const float* bhh1 = (const float*)d_in[8];
    const float* wih2 = (const float*)d_in[9];
    const float* whh2 = (const float*)d_in[10];
    const float* bih2 = (const float*)d_in[11];
    const float* bhh2 = (const float*)d_in[12];
    float* out = (float*)d_out;

    rnn_fused<<<dim3(8192 / 32), dim3(768), 0, stream>>>(
        x, wih0, whh0, bih0, bhh0, wih1, whh1, bih1, bhh1,
        wih2, whh2, bih2, bhh2, out);
}